// Round 1
// baseline (595.389 us; speedup 1.0000x reference)
//
#include <hip/hip_runtime.h>

#define Bn 4
#define Cn 256
#define HWn 4096
#define CPn 64

#define BM 64
#define BN 64
#define BK 16

// ---------------------------------------------------------------------------
// Phase 1: proj[s,j,b,e,hw] = sum_c Wqkv[3s+j][e][c] * x[s][b][c][hw]
// Stored as Qb/Kb/Vb each laid out [s][b][e][hw]  (3*B*C*HW floats)
// ---------------------------------------------------------------------------
__global__ __launch_bounds__(256) void proj_gemm(
    const float* __restrict__ Tt, const float* __restrict__ Bt, const float* __restrict__ Mt,
    const float* __restrict__ Wqkv,
    float* __restrict__ Qb, float* __restrict__ Kb, float* __restrict__ Vb)
{
    const int sj = blockIdx.z;           // 0..8
    const int s  = sj / 3, j = sj % 3;
    const int bb = blockIdx.y;           // batch
    const int tm = blockIdx.x & 3;       // 4 M tiles (256/64)
    const int tn = blockIdx.x >> 2;      // 64 N tiles (4096/64)

    const float* X  = (s == 0 ? Tt : (s == 1 ? Bt : Mt)) + (size_t)bb * Cn * HWn;
    const float* Wp = Wqkv + (size_t)sj * Cn * Cn;
    float* Out = (j == 0 ? Qb : (j == 1 ? Kb : Vb)) + (size_t)(s * Bn + bb) * Cn * HWn;

    const int e0  = tm * BM;
    const int hw0 = tn * BN;

    __shared__ float As[BK][BM];   // As[k][e]
    __shared__ float Bs[BK][BN];   // Bs[k][hw]

    const int t  = threadIdx.x;
    const int ty = t >> 4, tx = t & 15;

    float acc[4][4] = {};

    for (int k0 = 0; k0 < Cn; k0 += BK) {
        // Load A tile: 64 rows(e) x 16 cols(k).  256 threads x 1 float4.
        {
            const int e  = t >> 2;          // 0..63
            const int kq = (t & 3) * 4;     // 0,4,8,12
            const float4 a = *(const float4*)(Wp + (size_t)(e0 + e) * Cn + k0 + kq);
            As[kq + 0][e] = a.x; As[kq + 1][e] = a.y;
            As[kq + 2][e] = a.z; As[kq + 3][e] = a.w;
        }
        // Load B tile: 16 rows(k) x 64 cols(hw). 256 threads x 1 float4, coalesced.
        {
            const int r  = t >> 4;          // 0..15
            const int cq = (t & 15) * 4;    // 0..60
            *(float4*)(&Bs[r][cq]) = *(const float4*)(X + (size_t)(k0 + r) * HWn + hw0 + cq);
        }
        __syncthreads();
        #pragma unroll
        for (int k = 0; k < BK; ++k) {
            const float4 a4 = *(const float4*)(&As[k][ty * 4]);
            const float4 b4 = *(const float4*)(&Bs[k][tx * 4]);
            const float a[4] = {a4.x, a4.y, a4.z, a4.w};
            const float b[4] = {b4.x, b4.y, b4.z, b4.w};
            #pragma unroll
            for (int i = 0; i < 4; ++i)
                #pragma unroll
                for (int jj = 0; jj < 4; ++jj)
                    acc[i][jj] = fmaf(a[i], b[jj], acc[i][jj]);
        }
        __syncthreads();
    }

    #pragma unroll
    for (int i = 0; i < 4; ++i) {
        float4 v = {acc[i][0], acc[i][1], acc[i][2], acc[i][3]};
        *(float4*)(Out + (size_t)(e0 + ty * 4 + i) * HWn + hw0 + tx * 4) = v;
    }
}

// ---------------------------------------------------------------------------
// Phase 2: for each of 9 (tensor,s) groups, 3 stacked W_red[idx] (CP x C) GEMMs
// against the (C x HW) input, relu, then fused mean+max pooling via atomics.
// pool arrays indexed [tt][idx][b][cp], tt: 0=Q(->g) 1=K(->f) 2=V(->h)
// ---------------------------------------------------------------------------
__global__ __launch_bounds__(256) void red_pool(
    const float* __restrict__ Qb, const float* __restrict__ Kb, const float* __restrict__ Vb,
    const float* __restrict__ Wred,
    float* __restrict__ pool_sum, unsigned int* __restrict__ pool_max)
{
    const int g  = blockIdx.z;           // 0..8
    const int tt = g / 3, s = g % 3;
    const int bb = blockIdx.y;
    const int tm = blockIdx.x % 3;       // which W_red of the stacked 3
    const int tn = blockIdx.x / 3;       // 64 N tiles

    // idx mapping: Q/V use JIDX (s + 3*sub), K uses IIDX (3*s + sub)
    const int idx = (tt == 1) ? (3 * s + tm) : (s + 3 * tm);

    const float* X = (tt == 0 ? Qb : (tt == 1 ? Kb : Vb)) + (size_t)(s * Bn + bb) * Cn * HWn;
    const float* Wp = Wred + (size_t)idx * CPn * Cn;   // 64 rows x 256

    const int hw0 = tn * BN;

    __shared__ float As[BK][BM];
    __shared__ float Bs[BK][BN];

    const int t  = threadIdx.x;
    const int ty = t >> 4, tx = t & 15;

    float acc[4][4] = {};

    for (int k0 = 0; k0 < Cn; k0 += BK) {
        {
            const int e  = t >> 2;
            const int kq = (t & 3) * 4;
            const float4 a = *(const float4*)(Wp + (size_t)e * Cn + k0 + kq);
            As[kq + 0][e] = a.x; As[kq + 1][e] = a.y;
            As[kq + 2][e] = a.z; As[kq + 3][e] = a.w;
        }
        {
            const int r  = t >> 4;
            const int cq = (t & 15) * 4;
            *(float4*)(&Bs[r][cq]) = *(const float4*)(X + (size_t)(k0 + r) * HWn + hw0 + cq);
        }
        __syncthreads();
        #pragma unroll
        for (int k = 0; k < BK; ++k) {
            const float4 a4 = *(const float4*)(&As[k][ty * 4]);
            const float4 b4 = *(const float4*)(&Bs[k][tx * 4]);
            const float a[4] = {a4.x, a4.y, a4.z, a4.w};
            const float b[4] = {b4.x, b4.y, b4.z, b4.w};
            #pragma unroll
            for (int i = 0; i < 4; ++i)
                #pragma unroll
                for (int jj = 0; jj < 4; ++jj)
                    acc[i][jj] = fmaf(a[i], b[jj], acc[i][jj]);
        }
        __syncthreads();
    }

    // relu + row-wise partial pool over this 64-wide hw tile
    #pragma unroll
    for (int i = 0; i < 4; ++i) {
        float r0 = fmaxf(acc[i][0], 0.f), r1 = fmaxf(acc[i][1], 0.f);
        float r2 = fmaxf(acc[i][2], 0.f), r3 = fmaxf(acc[i][3], 0.f);
        float rs = (r0 + r1) + (r2 + r3);
        float rm = fmaxf(fmaxf(r0, r1), fmaxf(r2, r3));
        // reduce across the 16 tx lanes (contiguous lanes within the wave)
        #pragma unroll
        for (int off = 1; off < 16; off <<= 1) {
            rs += __shfl_xor(rs, off);
            rm  = fmaxf(rm, __shfl_xor(rm, off));
        }
        if (tx == 0) {
            const int cp   = ty * 4 + i;
            const int pidx = ((tt * 9 + idx) * Bn + bb) * CPn + cp;
            atomicAdd(pool_sum + pidx, rs);
            atomicMax(pool_max + pidx, __float_as_uint(rm));  // relu => >= 0, bits-ordered
        }
    }
}

// ---------------------------------------------------------------------------
// Phase 3: per (idx,b): f,g,h -> softmax over i -> vout -> o = sigmoid(W_rec vout)
// accumulate coefA[s_j][b][c] (+o, applies to Q and V) and coefK[s_i][b][c].
// ---------------------------------------------------------------------------
__global__ __launch_bounds__(256) void attn_small(
    const float* __restrict__ pool_sum, const unsigned int* __restrict__ pool_max,
    const float* __restrict__ Wrec,
    float* __restrict__ coefA, float* __restrict__ coefK)
{
    const int idx = blockIdx.x / Bn;   // 0..8
    const int bb  = blockIdx.x % Bn;
    __shared__ float ff[CPn], gg[CPn], hh[CPn], vout[CPn];
    const int t = threadIdx.x;

    if (t < CPn) {
        int base;
        base = ((0 * 9 + idx) * Bn + bb) * CPn + t;
        gg[t] = pool_sum[base] * (1.0f / HWn) + __uint_as_float(pool_max[base]);
        base = ((1 * 9 + idx) * Bn + bb) * CPn + t;
        ff[t] = pool_sum[base] * (1.0f / HWn) + __uint_as_float(pool_max[base]);
        base = ((2 * 9 + idx) * Bn + bb) * CPn + t;
        hh[t] = pool_sum[base] * (1.0f / HWn) + __uint_as_float(pool_max[base]);
    }
    __syncthreads();

    if (t < CPn) {
        const float gj = gg[t];
        float mx = -1e30f;
        for (int i = 0; i < CPn; ++i) mx = fmaxf(mx, ff[i] * gj);
        float den = 0.f, num = 0.f;
        for (int i = 0; i < CPn; ++i) {
            const float e = expf(ff[i] * gj - mx);
            den += e;
            num += hh[i] * e;
        }
        vout[t] = num / den;
    }
    __syncthreads();

    {
        const float* wr = Wrec + ((size_t)idx * Cn + t) * CPn;
        float a = 0.f;
        for (int e = 0; e < CPn; ++e) a += vout[e] * wr[e];
        const float o = 1.0f / (1.0f + expf(-a));
        const int sj = idx % 3;  // JIDX
        const int si = idx / 3;  // IIDX
        atomicAdd(coefA + (sj * Bn + bb) * Cn + t, o);
        atomicAdd(coefK + (si * Bn + bb) * Cn + t, o);
    }
}

// ---------------------------------------------------------------------------
// Phase 4: out[b,c,hw] = sum_s coefA[s,b,c]*(Q+V)[s,b,c,hw] + coefK[s,b,c]*K[s,b,c,hw]
// ---------------------------------------------------------------------------
__global__ __launch_bounds__(256) void final_out(
    const float* __restrict__ Qb, const float* __restrict__ Kb, const float* __restrict__ Vb,
    const float* __restrict__ coefA, const float* __restrict__ coefK,
    float* __restrict__ out)
{
    const int bc = blockIdx.x;            // 0..B*C-1
    const int bb = bc >> 8, c = bc & 255;
    float ca[3], ck[3];
    size_t ro[3];
    #pragma unroll
    for (int s = 0; s < 3; ++s) {
        ca[s] = coefA[(s * Bn + bb) * Cn + c];
        ck[s] = coefK[(s * Bn + bb) * Cn + c];
        ro[s] = ((size_t)(s * Bn + bb) * Cn + c) * HWn;
    }
    const size_t ob = (size_t)bc * HWn;
    for (int hw = threadIdx.x * 4; hw < HWn; hw += 256 * 4) {
        float4 acc = {0.f, 0.f, 0.f, 0.f};
        #pragma unroll
        for (int s = 0; s < 3; ++s) {
            const float4 q = *(const float4*)(Qb + ro[s] + hw);
            const float4 k = *(const float4*)(Kb + ro[s] + hw);
            const float4 v = *(const float4*)(Vb + ro[s] + hw);
            acc.x += ca[s] * (q.x + v.x) + ck[s] * k.x;
            acc.y += ca[s] * (q.y + v.y) + ck[s] * k.y;
            acc.z += ca[s] * (q.z + v.z) + ck[s] * k.z;
            acc.w += ca[s] * (q.w + v.w) + ck[s] * k.w;
        }
        *(float4*)(out + ob + hw) = acc;
    }
}

extern "C" void kernel_launch(void* const* d_in, const int* in_sizes, int n_in,
                              void* d_out, int out_size, void* d_ws, size_t ws_size,
                              hipStream_t stream)
{
    const float* Tt   = (const float*)d_in[0];
    const float* Bt   = (const float*)d_in[1];
    const float* Mt   = (const float*)d_in[2];
    const float* Wqkv = (const float*)d_in[3];
    const float* Wred = (const float*)d_in[4];
    const float* Wrec = (const float*)d_in[5];
    float* out = (float*)d_out;
    float* ws  = (float*)d_ws;

    const size_t SZ = (size_t)3 * Bn * Cn * HWn;    // one of Q/K/V
    float* Qb = ws;
    float* Kb = ws + SZ;
    float* Vb = ws + 2 * SZ;
    float* pool_sum = ws + 3 * SZ;                      // 3*9*B*CP floats
    const size_t PSZ = (size_t)3 * 9 * Bn * CPn;
    unsigned int* pool_max = (unsigned int*)(ws + 3 * SZ + PSZ);
    float* coefA = ws + 3 * SZ + 2 * PSZ;               // 3*B*C floats
    float* coefK = coefA + (size_t)3 * Bn * Cn;

    // zero the accumulation buffers (ws is poisoned 0xAA before every launch)
    hipMemsetAsync(ws + 3 * SZ, 0, (2 * PSZ + 2 * (size_t)3 * Bn * Cn) * sizeof(float), stream);

    proj_gemm<<<dim3(256, Bn, 9), 256, 0, stream>>>(Tt, Bt, Mt, Wqkv, Qb, Kb, Vb);
    red_pool <<<dim3(192, Bn, 9), 256, 0, stream>>>(Qb, Kb, Vb, Wred, pool_sum, pool_max);
    attn_small<<<9 * Bn, 256, 0, stream>>>(pool_sum, pool_max, Wrec, coefA, coefK);
    final_out<<<Bn * Cn, 256, 0, stream>>>(Qb, Kb, Vb, coefA, coefK, out);
}

// Round 2
// 270.444 us; speedup vs baseline: 2.2015x; 2.2015x over previous
//
#include <hip/hip_runtime.h>

#define Bn 4
#define Cn 256
#define HWn 4096
#define CPn 64

typedef unsigned short u16;
typedef unsigned int u32;

using short8  = __attribute__((ext_vector_type(8))) short;
using floatx4 = __attribute__((ext_vector_type(4))) float;

static __device__ __forceinline__ u16 f2bf(float f) {
    union { float f; u32 u; } v; v.f = f;
    u32 r = (v.u + 0x7FFFu + ((v.u >> 16) & 1u)) >> 16;
    return (u16)r;
}

// ---------------------------------------------------------------------------
// K1: fp32 (C x HW) -> bf16 (HW x C) transpose per (s,b).  xT[s][b][hw][c]
// ---------------------------------------------------------------------------
__global__ __launch_bounds__(256) void convert_transpose(
    const float* __restrict__ Tt, const float* __restrict__ Bt, const float* __restrict__ Mt,
    u16* __restrict__ xT)
{
    const int s  = blockIdx.z, b = blockIdx.y;
    const int ct = blockIdx.x & 3, hwt = blockIdx.x >> 2;
    const int c0 = ct * 64, hw0 = hwt * 64;
    const float* X = (s == 0 ? Tt : (s == 1 ? Bt : Mt)) + (size_t)b * Cn * HWn;

    __shared__ u16 T[64][72];
    const int t = threadIdx.x;
    const int cl = t >> 2, q = t & 3;

    const float* src = X + (size_t)(c0 + cl) * HWn + hw0 + q * 16;
    #pragma unroll
    for (int u = 0; u < 4; ++u) {
        const float4 v = *(const float4*)(src + u * 4);
        T[cl][q * 16 + u * 4 + 0] = f2bf(v.x);
        T[cl][q * 16 + u * 4 + 1] = f2bf(v.y);
        T[cl][q * 16 + u * 4 + 2] = f2bf(v.z);
        T[cl][q * 16 + u * 4 + 3] = f2bf(v.w);
    }
    __syncthreads();

    const int wl = t >> 2;
    u16* dst = xT + ((size_t)((s * Bn + b) * HWn) + hw0 + wl) * Cn + c0 + q * 16;
    #pragma unroll
    for (int u = 0; u < 2; ++u) {
        u32 w0 = (u32)T[q * 16 + u * 8 + 0][wl] | ((u32)T[q * 16 + u * 8 + 1][wl] << 16);
        u32 w1 = (u32)T[q * 16 + u * 8 + 2][wl] | ((u32)T[q * 16 + u * 8 + 3][wl] << 16);
        u32 w2 = (u32)T[q * 16 + u * 8 + 4][wl] | ((u32)T[q * 16 + u * 8 + 5][wl] << 16);
        u32 w3 = (u32)T[q * 16 + u * 8 + 6][wl] | ((u32)T[q * 16 + u * 8 + 7][wl] << 16);
        uint4 pk = {w0, w1, w2, w3};
        *(uint4*)(dst + u * 8) = pk;
    }
}

// ---------------------------------------------------------------------------
// K2: compose CW[s] (576 x 256) bf16 = stack of Wred[idx] @ Wqkv[3s+tt].
// rows [tt*192 + m*64 + r], idx = (tt==1)? 3s+m : 3m+s.  fp32 math.
// ---------------------------------------------------------------------------
__global__ __launch_bounds__(256) void compose_red(
    const float* __restrict__ Wqkv, const float* __restrict__ Wred,
    u16* __restrict__ CW)
{
    const int s  = blockIdx.z;
    const int tt = blockIdx.y / 3, m3 = blockIdx.y % 3;
    const int c0 = blockIdx.x * 64;
    const int idx = (tt == 1) ? (3 * s + m3) : (3 * m3 + s);

    const float* A = Wred + (size_t)idx * CPn * Cn;          // 64 x 256 (r,e)
    const float* Bm = Wqkv + (size_t)(3 * s + tt) * Cn * Cn; // 256 x 256 (e,c)

    __shared__ float As[16][64];
    __shared__ float Bs[16][64];
    const int t = threadIdx.x;
    const int ty = t >> 4, tx = t & 15;
    float acc[4][4] = {};

    for (int k0 = 0; k0 < Cn; k0 += 16) {
        {
            const int r = t >> 2, eq = (t & 3) * 4;
            const float4 a = *(const float4*)(A + (size_t)r * Cn + k0 + eq);
            As[eq + 0][r] = a.x; As[eq + 1][r] = a.y; As[eq + 2][r] = a.z; As[eq + 3][r] = a.w;
        }
        {
            const int r = t >> 4, cq = (t & 15) * 4;
            *(float4*)(&Bs[r][cq]) = *(const float4*)(Bm + (size_t)(k0 + r) * Cn + c0 + cq);
        }
        __syncthreads();
        #pragma unroll
        for (int k = 0; k < 16; ++k) {
            const float4 a4 = *(const float4*)(&As[k][ty * 4]);
            const float4 b4 = *(const float4*)(&Bs[k][tx * 4]);
            const float a[4] = {a4.x, a4.y, a4.z, a4.w};
            const float bb[4] = {b4.x, b4.y, b4.z, b4.w};
            #pragma unroll
            for (int i = 0; i < 4; ++i)
                #pragma unroll
                for (int j = 0; j < 4; ++j)
                    acc[i][j] = fmaf(a[i], bb[j], acc[i][j]);
        }
        __syncthreads();
    }

    u16* out = CW + (size_t)s * 576 * Cn;
    #pragma unroll
    for (int i = 0; i < 4; ++i) {
        const int row = tt * 192 + m3 * 64 + ty * 4 + i;
        unsigned long long pk =
            (unsigned long long)f2bf(acc[i][0]) |
            ((unsigned long long)f2bf(acc[i][1]) << 16) |
            ((unsigned long long)f2bf(acc[i][2]) << 32) |
            ((unsigned long long)f2bf(acc[i][3]) << 48);
        *(unsigned long long*)(out + (size_t)row * Cn + c0 + tx * 4) = pk;
    }
}

// ---------------------------------------------------------------------------
// K3: per s: (576 x 256) @ (256 x 4096) per b, bf16 MFMA, relu + mean/max pool
// epilogue into pool_sum/pool_max[(tt*9+idx)*B+b][cp].
// ---------------------------------------------------------------------------
#define LDSP 264   // 256 + 8 bf16 pad

__global__ __launch_bounds__(256) void redpool_mfma(
    const u16* __restrict__ xT, const u16* __restrict__ CW,
    float* __restrict__ pool_sum, u32* __restrict__ pool_max)
{
    const int s  = blockIdx.z, b = blockIdx.y;
    const int mt = blockIdx.x >> 6, nt = blockIdx.x & 63;  // 9 x 64
    const int m0 = mt * 64, hw0 = nt * 64;

    const u16* Ap = CW + (size_t)s * 576 * Cn + (size_t)m0 * Cn;
    const u16* Bp = xT + ((size_t)((s * Bn + b) * HWn) + hw0) * Cn;

    __shared__ __align__(16) u16 As[64 * LDSP];
    __shared__ __align__(16) u16 Bs[64 * LDSP];
    const int t = threadIdx.x;

    #pragma unroll
    for (int u = 0; u < 8; ++u) {
        const int lin = u * 256 + t;
        const int row = lin >> 5, seg = lin & 31;
        *(uint4*)&As[row * LDSP + seg * 8] = *(const uint4*)(Ap + (size_t)row * Cn + seg * 8);
        *(uint4*)&Bs[row * LDSP + seg * 8] = *(const uint4*)(Bp + (size_t)row * Cn + seg * 8);
    }
    __syncthreads();

    const int w = t >> 6, lane = t & 63;
    const int rb = (w >> 1) * 32, cb = (w & 1) * 32;
    const int l15 = lane & 15, q = lane >> 4;

    floatx4 acc[2][2] = {};
    #pragma unroll
    for (int kk = 0; kk < 8; ++kk) {
        const int ks = kk * 32 + q * 8;
        const short8 a0 = *(const short8*)&As[(rb + l15) * LDSP + ks];
        const short8 a1 = *(const short8*)&As[(rb + 16 + l15) * LDSP + ks];
        const short8 b0 = *(const short8*)&Bs[(cb + l15) * LDSP + ks];
        const short8 b1 = *(const short8*)&Bs[(cb + 16 + l15) * LDSP + ks];
        acc[0][0] = __builtin_amdgcn_mfma_f32_16x16x32_bf16(a0, b0, acc[0][0], 0, 0, 0);
        acc[0][1] = __builtin_amdgcn_mfma_f32_16x16x32_bf16(a0, b1, acc[0][1], 0, 0, 0);
        acc[1][0] = __builtin_amdgcn_mfma_f32_16x16x32_bf16(a1, b0, acc[1][0], 0, 0, 0);
        acc[1][1] = __builtin_amdgcn_mfma_f32_16x16x32_bf16(a1, b1, acc[1][1], 0, 0, 0);
    }

    #pragma unroll
    for (int i = 0; i < 2; ++i) {
        #pragma unroll
        for (int r = 0; r < 4; ++r) {
            const float v0 = fmaxf(acc[i][0][r], 0.f);
            const float v1 = fmaxf(acc[i][1][r], 0.f);
            float rs = v0 + v1;
            float rm = fmaxf(v0, v1);
            #pragma unroll
            for (int off = 1; off < 16; off <<= 1) {
                rs += __shfl_xor(rs, off);
                rm = fmaxf(rm, __shfl_xor(rm, off));
            }
            if (l15 == 0) {
                const int lr = rb + 16 * i + q * 4 + r;
                const int R = m0 + lr;
                const int tt = R / 192, m3 = (R / 64) % 3, cp = R & 63;
                const int idx = (tt == 1) ? (3 * s + m3) : (3 * m3 + s);
                const int pidx = ((tt * 9 + idx) * Bn + b) * CPn + cp;
                atomicAdd(&pool_sum[pidx], rs);
                atomicMax(&pool_max[pidx], __float_as_uint(rm));
            }
        }
    }
}

// ---------------------------------------------------------------------------
// K4: tiny attention per (idx,b) -> coefA/coefK accumulation (fp32)
// ---------------------------------------------------------------------------
__global__ __launch_bounds__(256) void attn_small(
    const float* __restrict__ pool_sum, const u32* __restrict__ pool_max,
    const float* __restrict__ Wrec,
    float* __restrict__ coefA, float* __restrict__ coefK)
{
    const int idx = blockIdx.x / Bn;
    const int bb  = blockIdx.x % Bn;
    __shared__ float ff[CPn], gg[CPn], hh[CPn], vout[CPn];
    const int t = threadIdx.x;

    if (t < CPn) {
        int base;
        base = ((0 * 9 + idx) * Bn + bb) * CPn + t;
        gg[t] = pool_sum[base] * (1.0f / HWn) + __uint_as_float(pool_max[base]);
        base = ((1 * 9 + idx) * Bn + bb) * CPn + t;
        ff[t] = pool_sum[base] * (1.0f / HWn) + __uint_as_float(pool_max[base]);
        base = ((2 * 9 + idx) * Bn + bb) * CPn + t;
        hh[t] = pool_sum[base] * (1.0f / HWn) + __uint_as_float(pool_max[base]);
    }
    __syncthreads();

    if (t < CPn) {
        const float gj = gg[t];
        float mx = -1e30f;
        for (int i = 0; i < CPn; ++i) mx = fmaxf(mx, ff[i] * gj);
        float den = 0.f, num = 0.f;
        for (int i = 0; i < CPn; ++i) {
            const float e = expf(ff[i] * gj - mx);
            den += e;
            num += hh[i] * e;
        }
        vout[t] = num / den;
    }
    __syncthreads();

    {
        const float* wr = Wrec + ((size_t)idx * Cn + t) * CPn;
        float a = 0.f;
        for (int e = 0; e < CPn; ++e) a += vout[e] * wr[e];
        const float o = 1.0f / (1.0f + expf(-a));
        const int sj = idx % 3;
        const int si = idx / 3;
        atomicAdd(coefA + (sj * Bn + bb) * Cn + t, o);
        atomicAdd(coefK + (si * Bn + bb) * Cn + t, o);
    }
}

// ---------------------------------------------------------------------------
// K5: build composed output matrix M[b][m][s*256+c] bf16
//   = coefA[s,b,m]*(Wq+Wv)[m][c] + coefK[s,b,m]*Wk[m][c]
// ---------------------------------------------------------------------------
__global__ __launch_bounds__(256) void build_M(
    const float* __restrict__ Wqkv,
    const float* __restrict__ coefA, const float* __restrict__ coefK,
    u16* __restrict__ Mm)
{
    const int s = blockIdx.x >> 8, m = blockIdx.x & 255;
    const int b = blockIdx.y;
    const int t = threadIdx.x;
    const float cA = coefA[(s * Bn + b) * Cn + m];
    const float cK = coefK[(s * Bn + b) * Cn + m];
    const float wq = Wqkv[((size_t)(3 * s + 0) * Cn + m) * Cn + t];
    const float wk = Wqkv[((size_t)(3 * s + 1) * Cn + m) * Cn + t];
    const float wv = Wqkv[((size_t)(3 * s + 2) * Cn + m) * Cn + t];
    Mm[((size_t)(b * 256 + m)) * 768 + s * 256 + t] = f2bf(cA * (wq + wv) + cK * wk);
}

// ---------------------------------------------------------------------------
// K6: out[b] (256 x 4096) = Mm[b] (256 x 768) @ xcat[b] (768 x 4096), fp32 out
// ---------------------------------------------------------------------------
__global__ __launch_bounds__(256) void final_mfma(
    const u16* __restrict__ xT, const u16* __restrict__ Mm,
    float* __restrict__ out)
{
    const int b  = blockIdx.y;
    const int mt = blockIdx.x >> 6, nt = blockIdx.x & 63;  // 4 x 64
    const int m0 = mt * 64, hw0 = nt * 64;

    __shared__ __align__(16) u16 As[64 * LDSP];
    __shared__ __align__(16) u16 Bs[64 * LDSP];
    const int t = threadIdx.x;
    const int w = t >> 6, lane = t & 63;
    const int rb = (w >> 1) * 32, cb = (w & 1) * 32;
    const int l15 = lane & 15, q = lane >> 4;

    floatx4 acc[2][2] = {};

    for (int s = 0; s < 3; ++s) {
        const u16* Ap = Mm + (size_t)(b * 256 + m0) * 768 + s * 256;
        const u16* Bp = xT + ((size_t)((s * Bn + b) * HWn) + hw0) * Cn;
        __syncthreads();
        #pragma unroll
        for (int u = 0; u < 8; ++u) {
            const int lin = u * 256 + t;
            const int row = lin >> 5, seg = lin & 31;
            *(uint4*)&As[row * LDSP + seg * 8] = *(const uint4*)(Ap + (size_t)row * 768 + seg * 8);
            *(uint4*)&Bs[row * LDSP + seg * 8] = *(const uint4*)(Bp + (size_t)row * Cn + seg * 8);
        }
        __syncthreads();
        #pragma unroll
        for (int kk = 0; kk < 8; ++kk) {
            const int ks = kk * 32 + q * 8;
            const short8 a0 = *(const short8*)&As[(rb + l15) * LDSP + ks];
            const short8 a1 = *(const short8*)&As[(rb + 16 + l15) * LDSP + ks];
            const short8 b0 = *(const short8*)&Bs[(cb + l15) * LDSP + ks];
            const short8 b1 = *(const short8*)&Bs[(cb + 16 + l15) * LDSP + ks];
            acc[0][0] = __builtin_amdgcn_mfma_f32_16x16x32_bf16(a0, b0, acc[0][0], 0, 0, 0);
            acc[0][1] = __builtin_amdgcn_mfma_f32_16x16x32_bf16(a0, b1, acc[0][1], 0, 0, 0);
            acc[1][0] = __builtin_amdgcn_mfma_f32_16x16x32_bf16(a1, b0, acc[1][0], 0, 0, 0);
            acc[1][1] = __builtin_amdgcn_mfma_f32_16x16x32_bf16(a1, b1, acc[1][1], 0, 0, 0);
        }
    }

    #pragma unroll
    for (int i = 0; i < 2; ++i)
        #pragma unroll
        for (int j = 0; j < 2; ++j)
            #pragma unroll
            for (int r = 0; r < 4; ++r) {
                const int lr = rb + 16 * i + q * 4 + r;
                const int lc = cb + 16 * j + l15;
                out[((size_t)(b * 256) + m0 + lr) * HWn + hw0 + lc] = acc[i][j][r];
            }
}

extern "C" void kernel_launch(void* const* d_in, const int* in_sizes, int n_in,
                              void* d_out, int out_size, void* d_ws, size_t ws_size,
                              hipStream_t stream)
{
    const float* Tt   = (const float*)d_in[0];
    const float* Bt   = (const float*)d_in[1];
    const float* Mt   = (const float*)d_in[2];
    const float* Wqkv = (const float*)d_in[3];
    const float* Wred = (const float*)d_in[4];
    const float* Wrec = (const float*)d_in[5];
    float* out = (float*)d_out;

    unsigned char* p = (unsigned char*)d_ws;
    u16* xT = (u16*)p;            p += (size_t)3 * Bn * HWn * Cn * 2;   // 25.2 MB
    u16* CW = (u16*)p;            p += (size_t)3 * 576 * Cn * 2;        // 884 KB
    u16* Mm = (u16*)p;            p += (size_t)Bn * 256 * 768 * 2;      // 1.57 MB
    float* pool_sum = (float*)p;  p += (size_t)27 * Bn * CPn * 4;
    u32*   pool_max = (u32*)p;    p += (size_t)27 * Bn * CPn * 4;
    float* coefA = (float*)p;     p += (size_t)3 * Bn * Cn * 4;
    float* coefK = (float*)p;     p += (size_t)3 * Bn * Cn * 4;

    // zero the accumulation buffers (pool_sum..coefK contiguous)
    hipMemsetAsync(pool_sum,
                   0,
                   (size_t)(27 * Bn * CPn * 2 + 3 * Bn * Cn * 2) * 4,
                   stream);

    compose_red      <<<dim3(4, 9, 3),        256, 0, stream>>>(Wqkv, Wred, CW);
    convert_transpose<<<dim3(256, Bn, 3),     256, 0, stream>>>(Tt, Bt, Mt, xT);
    redpool_mfma     <<<dim3(576, Bn, 3),     256, 0, stream>>>(xT, CW, pool_sum, pool_max);
    attn_small       <<<9 * Bn,               256, 0, stream>>>(pool_sum, pool_max, Wrec, coefA, coefK);
    build_M          <<<dim3(768, Bn),        256, 0, stream>>>(Wqkv, coefA, coefK, Mm);
    final_mfma       <<<dim3(256, Bn),        256, 0, stream>>>(xT, Mm, out);
}

// Round 3
// 193.747 us; speedup vs baseline: 3.0730x; 1.3959x over previous
//
#include <hip/hip_runtime.h>

#define Bn 4
#define Cn 256
#define HWn 4096
#define CPn 64
#define MP 640   // CW rows padded 576 -> 640 (5 x 128)

typedef unsigned short u16;
typedef unsigned int u32;

using short8  = __attribute__((ext_vector_type(8))) short;
using floatx4 = __attribute__((ext_vector_type(4))) float;

static __device__ __forceinline__ u16 f2bf(float f) {
    union { float f; u32 u; } v; v.f = f;
    u32 r = (v.u + 0x7FFFu + ((v.u >> 16) & 1u)) >> 16;
    return (u16)r;
}

// async global -> LDS, 16 B per lane. LDS dest = wave-uniform base + lane*16.
static __device__ __forceinline__ void gld16(const u16* g, u16* l) {
    __builtin_amdgcn_global_load_lds(
        (const __attribute__((address_space(1))) u32*)g,
        (__attribute__((address_space(3))) u32*)l, 16, 0, 0);
}

// ---------------------------------------------------------------------------
// K1: fp32 (C x HW) -> bf16 (HW x C) transpose per (s,b).  xT[s][b][hw][c]
// ---------------------------------------------------------------------------
__global__ __launch_bounds__(256) void convert_transpose(
    const float* __restrict__ Tt, const float* __restrict__ Bt, const float* __restrict__ Mt,
    u16* __restrict__ xT)
{
    const int s  = blockIdx.z, b = blockIdx.y;
    const int ct = blockIdx.x & 3, hwt = blockIdx.x >> 2;
    const int c0 = ct * 64, hw0 = hwt * 64;
    const float* X = (s == 0 ? Tt : (s == 1 ? Bt : Mt)) + (size_t)b * Cn * HWn;

    __shared__ u16 T[64][72];
    const int t = threadIdx.x;
    const int cl = t >> 2, q = t & 3;

    const float* src = X + (size_t)(c0 + cl) * HWn + hw0 + q * 16;
    #pragma unroll
    for (int u = 0; u < 4; ++u) {
        const float4 v = *(const float4*)(src + u * 4);
        T[cl][q * 16 + u * 4 + 0] = f2bf(v.x);
        T[cl][q * 16 + u * 4 + 1] = f2bf(v.y);
        T[cl][q * 16 + u * 4 + 2] = f2bf(v.z);
        T[cl][q * 16 + u * 4 + 3] = f2bf(v.w);
    }
    __syncthreads();

    const int wl = t >> 2;
    u16* dst = xT + ((size_t)((s * Bn + b) * HWn) + hw0 + wl) * Cn + c0 + q * 16;
    #pragma unroll
    for (int u = 0; u < 2; ++u) {
        u32 w0 = (u32)T[q * 16 + u * 8 + 0][wl] | ((u32)T[q * 16 + u * 8 + 1][wl] << 16);
        u32 w1 = (u32)T[q * 16 + u * 8 + 2][wl] | ((u32)T[q * 16 + u * 8 + 3][wl] << 16);
        u32 w2 = (u32)T[q * 16 + u * 8 + 4][wl] | ((u32)T[q * 16 + u * 8 + 5][wl] << 16);
        u32 w3 = (u32)T[q * 16 + u * 8 + 6][wl] | ((u32)T[q * 16 + u * 8 + 7][wl] << 16);
        uint4 pk = {w0, w1, w2, w3};
        *(uint4*)(dst + u * 8) = pk;
    }
}

// ---------------------------------------------------------------------------
// K2: compose CWp[s] (640 x 256) bf16 = stack of Wred[idx] @ Wqkv[3s+tt].
// rows [tt*192 + m*64 + r], idx = (tt==1)? 3s+m : 3m+s.  rows 576..639 = 0 (memset).
// ---------------------------------------------------------------------------
__global__ __launch_bounds__(256) void compose_red(
    const float* __restrict__ Wqkv, const float* __restrict__ Wred,
    u16* __restrict__ CWp)
{
    const int s  = blockIdx.z;
    const int tt = blockIdx.y / 3, m3 = blockIdx.y % 3;
    const int c0 = blockIdx.x * 64;
    const int idx = (tt == 1) ? (3 * s + m3) : (3 * m3 + s);

    const float* A = Wred + (size_t)idx * CPn * Cn;          // 64 x 256 (r,e)
    const float* Bm = Wqkv + (size_t)(3 * s + tt) * Cn * Cn; // 256 x 256 (e,c)

    __shared__ float As[16][64];
    __shared__ float Bs[16][64];
    const int t = threadIdx.x;
    const int ty = t >> 4, tx = t & 15;
    float acc[4][4] = {};

    for (int k0 = 0; k0 < Cn; k0 += 16) {
        {
            const int r = t >> 2, eq = (t & 3) * 4;
            const float4 a = *(const float4*)(A + (size_t)r * Cn + k0 + eq);
            As[eq + 0][r] = a.x; As[eq + 1][r] = a.y; As[eq + 2][r] = a.z; As[eq + 3][r] = a.w;
        }
        {
            const int r = t >> 4, cq = (t & 15) * 4;
            *(float4*)(&Bs[r][cq]) = *(const float4*)(Bm + (size_t)(k0 + r) * Cn + c0 + cq);
        }
        __syncthreads();
        #pragma unroll
        for (int k = 0; k < 16; ++k) {
            const float4 a4 = *(const float4*)(&As[k][ty * 4]);
            const float4 b4 = *(const float4*)(&Bs[k][tx * 4]);
            const float a[4] = {a4.x, a4.y, a4.z, a4.w};
            const float bb[4] = {b4.x, b4.y, b4.z, b4.w};
            #pragma unroll
            for (int i = 0; i < 4; ++i)
                #pragma unroll
                for (int j = 0; j < 4; ++j)
                    acc[i][j] = fmaf(a[i], bb[j], acc[i][j]);
        }
        __syncthreads();
    }

    u16* out = CWp + (size_t)s * MP * Cn;
    #pragma unroll
    for (int i = 0; i < 4; ++i) {
        const int row = tt * 192 + m3 * 64 + ty * 4 + i;
        unsigned long long pk =
            (unsigned long long)f2bf(acc[i][0]) |
            ((unsigned long long)f2bf(acc[i][1]) << 16) |
            ((unsigned long long)f2bf(acc[i][2]) << 32) |
            ((unsigned long long)f2bf(acc[i][3]) << 48);
        *(unsigned long long*)(out + (size_t)row * Cn + c0 + tx * 4) = pk;
    }
}

// ---------------------------------------------------------------------------
// K3: per s: CWp (640 x 256) @ xT^T (256 x 16384), m97-style 128x128xBK64,
// global_load_lds staging, relu + mean/max pool epilogue.
// ---------------------------------------------------------------------------
__global__ __launch_bounds__(256) void redpool_mfma(
    const u16* __restrict__ xT, const u16* __restrict__ CWp,
    float* __restrict__ pool_sum, u32* __restrict__ pool_max)
{
    const int s  = blockIdx.z;
    const int mt = blockIdx.x >> 7, nt = blockIdx.x & 127;
    const int m0 = mt * 128, n0 = nt * 128;           // n = b*4096 + hw

    const u16* Ap = CWp + (size_t)s * MP * Cn;
    const u16* Bp = xT + (size_t)s * Bn * HWn * Cn;

    __shared__ __align__(16) u16 As[128 * 64];
    __shared__ __align__(16) u16 Bs[128 * 64];

    const int t = threadIdx.x;
    const int w = t >> 6, lane = t & 63;
    const int l15 = lane & 15, q = lane >> 4;
    const int srow = lane >> 3, scol = (lane & 7) * 8;   // staging: 8 rows x 64k per instr
    const int rb = (w >> 1) * 64, cb = (w & 1) * 64;

    floatx4 acc[4][4] = {};

    for (int k0 = 0; k0 < Cn; k0 += 64) {
        #pragma unroll
        for (int i = 0; i < 4; ++i) {
            const int r = w * 32 + i * 8;   // wave-uniform LDS row base
            gld16(Ap + (size_t)(m0 + r + srow) * Cn + k0 + scol, &As[r * 64]);
            gld16(Bp + (size_t)(n0 + r + srow) * Cn + k0 + scol, &Bs[r * 64]);
        }
        __syncthreads();
        #pragma unroll
        for (int kk = 0; kk < 2; ++kk) {
            const int ks = kk * 32 + q * 8;
            short8 af[4], bf[4];
            #pragma unroll
            for (int i = 0; i < 4; ++i) af[i] = *(const short8*)&As[(rb + i * 16 + l15) * 64 + ks];
            #pragma unroll
            for (int j = 0; j < 4; ++j) bf[j] = *(const short8*)&Bs[(cb + j * 16 + l15) * 64 + ks];
            #pragma unroll
            for (int i = 0; i < 4; ++i)
                #pragma unroll
                for (int j = 0; j < 4; ++j)
                    acc[i][j] = __builtin_amdgcn_mfma_f32_16x16x32_bf16(af[i], bf[j], acc[i][j], 0, 0, 0);
        }
        __syncthreads();
    }

    // relu + pool over this block's 128 cols (all same b)
    const int b = n0 >> 12;
    #pragma unroll
    for (int i = 0; i < 4; ++i) {
        #pragma unroll
        for (int r = 0; r < 4; ++r) {
            float rs = 0.f, rm = 0.f;
            #pragma unroll
            for (int j = 0; j < 4; ++j) {
                const float v = fmaxf(acc[i][j][r], 0.f);
                rs += v; rm = fmaxf(rm, v);
            }
            #pragma unroll
            for (int off = 1; off < 16; off <<= 1) {
                rs += __shfl_xor(rs, off);
                rm = fmaxf(rm, __shfl_xor(rm, off));
            }
            if (l15 == 0) {
                const int R = m0 + rb + i * 16 + q * 4 + r;
                if (R < 576) {
                    const int tt = R / 192, m3 = (R / 64) % 3, cp = R & 63;
                    const int idx = (tt == 1) ? (3 * s + m3) : (3 * m3 + s);
                    const int pidx = ((tt * 9 + idx) * Bn + b) * CPn + cp;
                    atomicAdd(&pool_sum[pidx], rs);
                    atomicMax(&pool_max[pidx], __float_as_uint(rm));
                }
            }
        }
    }
}

// ---------------------------------------------------------------------------
// K4: tiny attention per (idx,b) -> coefA/coefK accumulation (fp32)
// ---------------------------------------------------------------------------
__global__ __launch_bounds__(256) void attn_small(
    const float* __restrict__ pool_sum, const u32* __restrict__ pool_max,
    const float* __restrict__ Wrec,
    float* __restrict__ coefA, float* __restrict__ coefK)
{
    const int idx = blockIdx.x / Bn;
    const int bb  = blockIdx.x % Bn;
    __shared__ float ff[CPn], gg[CPn], hh[CPn], vout[CPn];
    const int t = threadIdx.x;

    if (t < CPn) {
        int base;
        base = ((0 * 9 + idx) * Bn + bb) * CPn + t;
        gg[t] = pool_sum[base] * (1.0f / HWn) + __uint_as_float(pool_max[base]);
        base = ((1 * 9 + idx) * Bn + bb) * CPn + t;
        ff[t] = pool_sum[base] * (1.0f / HWn) + __uint_as_float(pool_max[base]);
        base = ((2 * 9 + idx) * Bn + bb) * CPn + t;
        hh[t] = pool_sum[base] * (1.0f / HWn) + __uint_as_float(pool_max[base]);
    }
    __syncthreads();

    if (t < CPn) {
        const float gj = gg[t];
        float mx = -1e30f;
        for (int i = 0; i < CPn; ++i) mx = fmaxf(mx, ff[i] * gj);
        float den = 0.f, num = 0.f;
        for (int i = 0; i < CPn; ++i) {
            const float e = expf(ff[i] * gj - mx);
            den += e;
            num += hh[i] * e;
        }
        vout[t] = num / den;
    }
    __syncthreads();

    {
        const float* wr = Wrec + ((size_t)idx * Cn + t) * CPn;
        float a = 0.f;
        for (int e = 0; e < CPn; ++e) a += vout[e] * wr[e];
        const float o = 1.0f / (1.0f + expf(-a));
        const int sj = idx % 3;
        const int si = idx / 3;
        atomicAdd(coefA + (sj * Bn + bb) * Cn + t, o);
        atomicAdd(coefK + (si * Bn + bb) * Cn + t, o);
    }
}

// ---------------------------------------------------------------------------
// K5: build composed output matrix Mm[b][m][s*256+c] bf16
// ---------------------------------------------------------------------------
__global__ __launch_bounds__(256) void build_M(
    const float* __restrict__ Wqkv,
    const float* __restrict__ coefA, const float* __restrict__ coefK,
    u16* __restrict__ Mm)
{
    const int s = blockIdx.x >> 8, m = blockIdx.x & 255;
    const int b = blockIdx.y;
    const int t = threadIdx.x;
    const float cA = coefA[(s * Bn + b) * Cn + m];
    const float cK = coefK[(s * Bn + b) * Cn + m];
    const float wq = Wqkv[((size_t)(3 * s + 0) * Cn + m) * Cn + t];
    const float wk = Wqkv[((size_t)(3 * s + 1) * Cn + m) * Cn + t];
    const float wv = Wqkv[((size_t)(3 * s + 2) * Cn + m) * Cn + t];
    Mm[((size_t)(b * 256 + m)) * 768 + s * 256 + t] = f2bf(cA * (wq + wv) + cK * wk);
}

// ---------------------------------------------------------------------------
// K6: out[b] (256 x 4096) = Mm[b] (256 x 768) @ xcat[b]^T, 128x64 tiles, BK=64
// ---------------------------------------------------------------------------
__global__ __launch_bounds__(256) void final_mfma(
    const u16* __restrict__ xT, const u16* __restrict__ Mm,
    float* __restrict__ out)
{
    const int b  = blockIdx.y;
    const int mt = blockIdx.x >> 6, nt = blockIdx.x & 63;
    const int m0 = mt * 128, n0 = nt * 64;

    __shared__ __align__(16) u16 As[128 * 64];
    __shared__ __align__(16) u16 Bs[64 * 64];

    const int t = threadIdx.x;
    const int w = t >> 6, lane = t & 63;
    const int l15 = lane & 15, q = lane >> 4;
    const int srow = lane >> 3, scol = (lane & 7) * 8;
    const int rb = (w >> 1) * 64, cb = (w & 1) * 32;

    const u16* Apb = Mm + (size_t)(b * 256 + m0) * 768;

    floatx4 acc[4][2] = {};

    for (int k0 = 0; k0 < 768; k0 += 64) {
        const int s = k0 >> 8, c0 = k0 & 255;
        const u16* Bpb = xT + ((size_t)((s * Bn + b) * HWn) + n0) * Cn + c0;
        #pragma unroll
        for (int i = 0; i < 4; ++i) {
            const int r = w * 32 + i * 8;
            gld16(Apb + (size_t)(r + srow) * 768 + k0 + scol, &As[r * 64]);
        }
        {
            const int r = w * 16 + 0;
            gld16(Bpb + (size_t)(r + srow) * Cn + scol, &Bs[r * 64]);
            const int r2 = w * 16 + 8;
            gld16(Bpb + (size_t)(r2 + srow) * Cn + scol, &Bs[r2 * 64]);
        }
        __syncthreads();
        #pragma unroll
        for (int kk = 0; kk < 2; ++kk) {
            const int ks = kk * 32 + q * 8;
            short8 af[4], bf[2];
            #pragma unroll
            for (int i = 0; i < 4; ++i) af[i] = *(const short8*)&As[(rb + i * 16 + l15) * 64 + ks];
            #pragma unroll
            for (int j = 0; j < 2; ++j) bf[j] = *(const short8*)&Bs[(cb + j * 16 + l15) * 64 + ks];
            #pragma unroll
            for (int i = 0; i < 4; ++i)
                #pragma unroll
                for (int j = 0; j < 2; ++j)
                    acc[i][j] = __builtin_amdgcn_mfma_f32_16x16x32_bf16(af[i], bf[j], acc[i][j], 0, 0, 0);
        }
        __syncthreads();
    }

    #pragma unroll
    for (int i = 0; i < 4; ++i)
        #pragma unroll
        for (int j = 0; j < 2; ++j)
            #pragma unroll
            for (int r = 0; r < 4; ++r) {
                const int row = m0 + rb + i * 16 + q * 4 + r;
                const int col = n0 + cb + j * 16 + l15;
                out[((size_t)(b * 256) + row) * HWn + col] = acc[i][j][r];
            }
}

extern "C" void kernel_launch(void* const* d_in, const int* in_sizes, int n_in,
                              void* d_out, int out_size, void* d_ws, size_t ws_size,
                              hipStream_t stream)
{
    const float* Tt   = (const float*)d_in[0];
    const float* Bt   = (const float*)d_in[1];
    const float* Mt   = (const float*)d_in[2];
    const float* Wqkv = (const float*)d_in[3];
    const float* Wred = (const float*)d_in[4];
    const float* Wrec = (const float*)d_in[5];
    float* out = (float*)d_out;

    unsigned char* p = (unsigned char*)d_ws;
    u16* xT = (u16*)p;            p += (size_t)3 * Bn * HWn * Cn * 2;   // 25.2 MB
    u16* Mm = (u16*)p;            p += (size_t)Bn * 256 * 768 * 2;      // 1.57 MB
    unsigned char* zbase = p;
    u16* CWp = (u16*)p;           p += (size_t)3 * MP * Cn * 2;         // 983 KB
    float* pool_sum = (float*)p;  p += (size_t)27 * Bn * CPn * 4;
    u32*   pool_max = (u32*)p;    p += (size_t)27 * Bn * CPn * 4;
    float* coefA = (float*)p;     p += (size_t)3 * Bn * Cn * 4;
    float* coefK = (float*)p;     p += (size_t)3 * Bn * Cn * 4;
    const size_t zbytes = (size_t)(p - zbase);

    hipMemsetAsync(zbase, 0, zbytes, stream);

    compose_red      <<<dim3(4, 9, 3),    256, 0, stream>>>(Wqkv, Wred, CWp);
    convert_transpose<<<dim3(256, Bn, 3), 256, 0, stream>>>(Tt, Bt, Mt, xT);
    redpool_mfma     <<<dim3(640, 1, 3),  256, 0, stream>>>(xT, CWp, pool_sum, pool_max);
    attn_small       <<<9 * Bn,           256, 0, stream>>>(pool_sum, pool_max, Wrec, coefA, coefK);
    build_M          <<<dim3(768, Bn),    256, 0, stream>>>(Wqkv, coefA, coefK, Mm);
    final_mfma       <<<dim3(128, Bn),    256, 0, stream>>>(xT, Mm, out);
}

// Round 4
// 188.366 us; speedup vs baseline: 3.1608x; 1.0286x over previous
//
#include <hip/hip_runtime.h>

#define Bn 4
#define Cn 256
#define HWn 4096
#define CPn 64
#define MP 640   // CW rows padded 576 -> 640 (5 x 128)

typedef unsigned short u16;
typedef unsigned int u32;

using short8  = __attribute__((ext_vector_type(8))) short;
using floatx4 = __attribute__((ext_vector_type(4))) float;

static __device__ __forceinline__ u16 f2bf(float f) {
    union { float f; u32 u; } v; v.f = f;
    u32 r = (v.u + 0x7FFFu + ((v.u >> 16) & 1u)) >> 16;
    return (u16)r;
}

// async global -> LDS, 16 B per lane. LDS dest = wave-uniform base + lane*16.
static __device__ __forceinline__ void gld16(const u16* g, u16* l) {
    __builtin_amdgcn_global_load_lds(
        (const __attribute__((address_space(1))) u32*)g,
        (__attribute__((address_space(3))) u32*)l, 16, 0, 0);
}

// Pane layout: one pane = one MFMA fragment set = 64 lanes x 16B = 1 KB.
// pane p of a tile covers rows [rblk*16, rblk*16+16) x k-chunk kk (32 wide),
// p = rblk*2 + kk.  Lane l holds (row = l&15, k = kk*32 + (l>>4)*8 .. +7).
// Compute-side read for a fragment is then exactly base + lane*16B:
// contiguous -> bank-conflict-free.

// ---------------------------------------------------------------------------
// K1: fp32 (C x HW) -> bf16 (HW x C) transpose per (s,b).  xT[s][b][hw][c]
// ---------------------------------------------------------------------------
__global__ __launch_bounds__(256) void convert_transpose(
    const float* __restrict__ Tt, const float* __restrict__ Bt, const float* __restrict__ Mt,
    u16* __restrict__ xT)
{
    const int s  = blockIdx.z, b = blockIdx.y;
    const int ct = blockIdx.x & 3, hwt = blockIdx.x >> 2;
    const int c0 = ct * 64, hw0 = hwt * 64;
    const float* X = (s == 0 ? Tt : (s == 1 ? Bt : Mt)) + (size_t)b * Cn * HWn;

    __shared__ u16 T[64][72];
    const int t = threadIdx.x;
    const int cl = t >> 2, q = t & 3;

    const float* src = X + (size_t)(c0 + cl) * HWn + hw0 + q * 16;
    #pragma unroll
    for (int u = 0; u < 4; ++u) {
        const float4 v = *(const float4*)(src + u * 4);
        T[cl][q * 16 + u * 4 + 0] = f2bf(v.x);
        T[cl][q * 16 + u * 4 + 1] = f2bf(v.y);
        T[cl][q * 16 + u * 4 + 2] = f2bf(v.z);
        T[cl][q * 16 + u * 4 + 3] = f2bf(v.w);
    }
    __syncthreads();

    const int wl = t >> 2;
    u16* dst = xT + ((size_t)((s * Bn + b) * HWn) + hw0 + wl) * Cn + c0 + q * 16;
    #pragma unroll
    for (int u = 0; u < 2; ++u) {
        u32 w0 = (u32)T[q * 16 + u * 8 + 0][wl] | ((u32)T[q * 16 + u * 8 + 1][wl] << 16);
        u32 w1 = (u32)T[q * 16 + u * 8 + 2][wl] | ((u32)T[q * 16 + u * 8 + 3][wl] << 16);
        u32 w2 = (u32)T[q * 16 + u * 8 + 4][wl] | ((u32)T[q * 16 + u * 8 + 5][wl] << 16);
        u32 w3 = (u32)T[q * 16 + u * 8 + 6][wl] | ((u32)T[q * 16 + u * 8 + 7][wl] << 16);
        uint4 pk = {w0, w1, w2, w3};
        *(uint4*)(dst + u * 8) = pk;
    }
}

// ---------------------------------------------------------------------------
// K2: compose CWp[s] (640 x 256) bf16 = stack of Wred[idx] @ Wqkv[3s+tt].
// rows [tt*192 + m*64 + r], idx = (tt==1)? 3s+m : 3m+s.  rows 576..639 = 0 (memset).
// ---------------------------------------------------------------------------
__global__ __launch_bounds__(256) void compose_red(
    const float* __restrict__ Wqkv, const float* __restrict__ Wred,
    u16* __restrict__ CWp)
{
    const int s  = blockIdx.z;
    const int tt = blockIdx.y / 3, m3 = blockIdx.y % 3;
    const int c0 = blockIdx.x * 64;
    const int idx = (tt == 1) ? (3 * s + m3) : (3 * m3 + s);

    const float* A = Wred + (size_t)idx * CPn * Cn;          // 64 x 256 (r,e)
    const float* Bm = Wqkv + (size_t)(3 * s + tt) * Cn * Cn; // 256 x 256 (e,c)

    __shared__ float As[16][64];
    __shared__ float Bs[16][64];
    const int t = threadIdx.x;
    const int ty = t >> 4, tx = t & 15;
    float acc[4][4] = {};

    for (int k0 = 0; k0 < Cn; k0 += 16) {
        {
            const int r = t >> 2, eq = (t & 3) * 4;
            const float4 a = *(const float4*)(A + (size_t)r * Cn + k0 + eq);
            As[eq + 0][r] = a.x; As[eq + 1][r] = a.y; As[eq + 2][r] = a.z; As[eq + 3][r] = a.w;
        }
        {
            const int r = t >> 4, cq = (t & 15) * 4;
            *(float4*)(&Bs[r][cq]) = *(const float4*)(Bm + (size_t)(k0 + r) * Cn + c0 + cq);
        }
        __syncthreads();
        #pragma unroll
        for (int k = 0; k < 16; ++k) {
            const float4 a4 = *(const float4*)(&As[k][ty * 4]);
            const float4 b4 = *(const float4*)(&Bs[k][tx * 4]);
            const float a[4] = {a4.x, a4.y, a4.z, a4.w};
            const float bb[4] = {b4.x, b4.y, b4.z, b4.w};
            #pragma unroll
            for (int i = 0; i < 4; ++i)
                #pragma unroll
                for (int j = 0; j < 4; ++j)
                    acc[i][j] = fmaf(a[i], bb[j], acc[i][j]);
        }
        __syncthreads();
    }

    u16* out = CWp + (size_t)s * MP * Cn;
    #pragma unroll
    for (int i = 0; i < 4; ++i) {
        const int row = tt * 192 + m3 * 64 + ty * 4 + i;
        unsigned long long pk =
            (unsigned long long)f2bf(acc[i][0]) |
            ((unsigned long long)f2bf(acc[i][1]) << 16) |
            ((unsigned long long)f2bf(acc[i][2]) << 32) |
            ((unsigned long long)f2bf(acc[i][3]) << 48);
        *(unsigned long long*)(out + (size_t)row * Cn + c0 + tx * 4) = pk;
    }
}

// ---------------------------------------------------------------------------
// K3: per s: CWp (640 x 256) @ xT^T (256 x 16384).  Tile 128(M) x 256(N), BK=64.
// Pane-ordered LDS (conflict-free), global_load_lds staging, pooled epilogue.
// ---------------------------------------------------------------------------
__global__ __launch_bounds__(256, 2) void redpool_mfma(
    const u16* __restrict__ xT, const u16* __restrict__ CWp,
    float* __restrict__ pool_sum, u32* __restrict__ pool_max)
{
    const int s  = blockIdx.z;
    const int mt = blockIdx.x >> 6, nt = blockIdx.x & 63;
    const int m0 = mt * 128, n0 = nt * 256;           // n = b*4096 + hw

    const u16* Ap = CWp + (size_t)s * MP * Cn;
    const u16* Bp = xT + (size_t)s * Bn * HWn * Cn;

    __shared__ __align__(16) u16 As[16 * 512];   // 16 panes (128 rows x 64 k)
    __shared__ __align__(16) u16 Bs[32 * 512];   // 32 panes (256 rows x 64 k)

    const int t = threadIdx.x;
    const int w = t >> 6, lane = t & 63;
    const int l15 = lane & 15, q = lane >> 4;
    const int rb = (w >> 1) * 64, cb = (w & 1) * 128;

    floatx4 acc[4][8] = {};

    for (int k0 = 0; k0 < Cn; k0 += 64) {
        const u16* Asrc = Ap + (size_t)m0 * Cn + k0 + (size_t)l15 * Cn + q * 8;
        const u16* Bsrc = Bp + (size_t)n0 * Cn + k0 + (size_t)l15 * Cn + q * 8;
        #pragma unroll
        for (int pi = 0; pi < 4; ++pi) {          // A panes: 4 per wave
            const int p = w * 4 + pi;
            gld16(Asrc + (size_t)((p >> 1) * 16) * Cn + (p & 1) * 32, &As[p * 512]);
        }
        #pragma unroll
        for (int pi = 0; pi < 8; ++pi) {          // B panes: 8 per wave
            const int p = w * 8 + pi;
            gld16(Bsrc + (size_t)((p >> 1) * 16) * Cn + (p & 1) * 32, &Bs[p * 512]);
        }
        __syncthreads();
        #pragma unroll
        for (int kk = 0; kk < 2; ++kk) {
            short8 af[4], bf[8];
            #pragma unroll
            for (int i = 0; i < 4; ++i)
                af[i] = *(const short8*)&As[((((w >> 1) * 4 + i) << 1) + kk) * 512 + lane * 8];
            #pragma unroll
            for (int j = 0; j < 8; ++j)
                bf[j] = *(const short8*)&Bs[((((w & 1) * 8 + j) << 1) + kk) * 512 + lane * 8];
            #pragma unroll
            for (int i = 0; i < 4; ++i)
                #pragma unroll
                for (int j = 0; j < 8; ++j)
                    acc[i][j] = __builtin_amdgcn_mfma_f32_16x16x32_bf16(af[i], bf[j], acc[i][j], 0, 0, 0);
        }
        __syncthreads();
    }

    // relu + pool over this block's 256 cols (all same b)
    const int b = n0 >> 12;
    #pragma unroll
    for (int i = 0; i < 4; ++i) {
        #pragma unroll
        for (int r = 0; r < 4; ++r) {
            float rs = 0.f, rm = 0.f;
            #pragma unroll
            for (int j = 0; j < 8; ++j) {
                const float v = fmaxf(acc[i][j][r], 0.f);
                rs += v; rm = fmaxf(rm, v);
            }
            #pragma unroll
            for (int off = 1; off < 16; off <<= 1) {
                rs += __shfl_xor(rs, off);
                rm = fmaxf(rm, __shfl_xor(rm, off));
            }
            if (l15 == 0) {
                const int R = m0 + rb + i * 16 + q * 4 + r;
                if (R < 576) {
                    const int tt = R / 192, m3 = (R / 64) % 3, cp = R & 63;
                    const int idx = (tt == 1) ? (3 * s + m3) : (3 * m3 + s);
                    const int pidx = ((tt * 9 + idx) * Bn + b) * CPn + cp;
                    atomicAdd(&pool_sum[pidx], rs);
                    atomicMax(&pool_max[pidx], __float_as_uint(rm));
                }
            }
        }
    }
}

// ---------------------------------------------------------------------------
// K4: tiny attention per (idx,b) -> coefA/coefK accumulation (fp32)
// ---------------------------------------------------------------------------
__global__ __launch_bounds__(256) void attn_small(
    const float* __restrict__ pool_sum, const u32* __restrict__ pool_max,
    const float* __restrict__ Wrec,
    float* __restrict__ coefA, float* __restrict__ coefK)
{
    const int idx = blockIdx.x / Bn;
    const int bb  = blockIdx.x % Bn;
    __shared__ float ff[CPn], gg[CPn], hh[CPn], vout[CPn];
    const int t = threadIdx.x;

    if (t < CPn) {
        int base;
        base = ((0 * 9 + idx) * Bn + bb) * CPn + t;
        gg[t] = pool_sum[base] * (1.0f / HWn) + __uint_as_float(pool_max[base]);
        base = ((1 * 9 + idx) * Bn + bb) * CPn + t;
        ff[t] = pool_sum[base] * (1.0f / HWn) + __uint_as_float(pool_max[base]);
        base = ((2 * 9 + idx) * Bn + bb) * CPn + t;
        hh[t] = pool_sum[base] * (1.0f / HWn) + __uint_as_float(pool_max[base]);
    }
    __syncthreads();

    if (t < CPn) {
        const float gj = gg[t];
        float mx = -1e30f;
        for (int i = 0; i < CPn; ++i) mx = fmaxf(mx, ff[i] * gj);
        float den = 0.f, num = 0.f;
        for (int i = 0; i < CPn; ++i) {
            const float e = expf(ff[i] * gj - mx);
            den += e;
            num += hh[i] * e;
        }
        vout[t] = num / den;
    }
    __syncthreads();

    {
        const float* wr = Wrec + ((size_t)idx * Cn + t) * CPn;
        float a = 0.f;
        for (int e = 0; e < CPn; ++e) a += vout[e] * wr[e];
        const float o = 1.0f / (1.0f + expf(-a));
        const int sj = idx % 3;
        const int si = idx / 3;
        atomicAdd(coefA + (sj * Bn + bb) * Cn + t, o);
        atomicAdd(coefK + (si * Bn + bb) * Cn + t, o);
    }
}

// ---------------------------------------------------------------------------
// K5: build composed output matrix Mm[b][m][s*256+c] bf16
// ---------------------------------------------------------------------------
__global__ __launch_bounds__(256) void build_M(
    const float* __restrict__ Wqkv,
    const float* __restrict__ coefA, const float* __restrict__ coefK,
    u16* __restrict__ Mm)
{
    const int s = blockIdx.x >> 8, m = blockIdx.x & 255;
    const int b = blockIdx.y;
    const int t = threadIdx.x;
    const float cA = coefA[(s * Bn + b) * Cn + m];
    const float cK = coefK[(s * Bn + b) * Cn + m];
    const float wq = Wqkv[((size_t)(3 * s + 0) * Cn + m) * Cn + t];
    const float wk = Wqkv[((size_t)(3 * s + 1) * Cn + m) * Cn + t];
    const float wv = Wqkv[((size_t)(3 * s + 2) * Cn + m) * Cn + t];
    Mm[((size_t)(b * 256 + m)) * 768 + s * 256 + t] = f2bf(cA * (wq + wv) + cK * wk);
}

// ---------------------------------------------------------------------------
// K6: out[b] (256 x 4096) = Mm[b] (256 x 768) @ xcat[b]^T.
// Tile 128(M) x 128(N), BK=64, 12 K-iters, pane-ordered LDS.
// ---------------------------------------------------------------------------
__global__ __launch_bounds__(256, 2) void final_mfma(
    const u16* __restrict__ xT, const u16* __restrict__ Mm,
    float* __restrict__ out)
{
    const int b  = blockIdx.y;
    const int mt = blockIdx.x >> 5, nt = blockIdx.x & 31;
    const int m0 = mt * 128, n0 = nt * 128;

    __shared__ __align__(16) u16 As[16 * 512];
    __shared__ __align__(16) u16 Bs[16 * 512];

    const int t = threadIdx.x;
    const int w = t >> 6, lane = t & 63;
    const int l15 = lane & 15, q = lane >> 4;
    const int rb = (w >> 1) * 64, cb = (w & 1) * 64;

    const u16* Apb = Mm + (size_t)(b * 256 + m0) * 768;

    floatx4 acc[4][4] = {};

    for (int k0 = 0; k0 < 768; k0 += 64) {
        const int s = k0 >> 8, c0 = k0 & 255;
        const u16* Asrc = Apb + k0 + (size_t)l15 * 768 + q * 8;
        const u16* Bsrc = xT + ((size_t)((s * Bn + b) * HWn) + n0 + l15) * Cn + c0 + q * 8;
        #pragma unroll
        for (int pi = 0; pi < 4; ++pi) {
            const int p = w * 4 + pi;
            gld16(Asrc + (size_t)((p >> 1) * 16) * 768 + (p & 1) * 32, &As[p * 512]);
            gld16(Bsrc + (size_t)((p >> 1) * 16) * Cn + (p & 1) * 32, &Bs[p * 512]);
        }
        __syncthreads();
        #pragma unroll
        for (int kk = 0; kk < 2; ++kk) {
            short8 af[4], bf[4];
            #pragma unroll
            for (int i = 0; i < 4; ++i)
                af[i] = *(const short8*)&As[((((w >> 1) * 4 + i) << 1) + kk) * 512 + lane * 8];
            #pragma unroll
            for (int j = 0; j < 4; ++j)
                bf[j] = *(const short8*)&Bs[((((w & 1) * 4 + j) << 1) + kk) * 512 + lane * 8];
            #pragma unroll
            for (int i = 0; i < 4; ++i)
                #pragma unroll
                for (int j = 0; j < 4; ++j)
                    acc[i][j] = __builtin_amdgcn_mfma_f32_16x16x32_bf16(af[i], bf[j], acc[i][j], 0, 0, 0);
        }
        __syncthreads();
    }

    #pragma unroll
    for (int i = 0; i < 4; ++i)
        #pragma unroll
        for (int j = 0; j < 4; ++j)
            #pragma unroll
            for (int r = 0; r < 4; ++r) {
                const int row = m0 + rb + i * 16 + q * 4 + r;
                const int col = n0 + cb + j * 16 + l15;
                out[((size_t)(b * 256) + row) * HWn + col] = acc[i][j][r];
            }
}

extern "C" void kernel_launch(void* const* d_in, const int* in_sizes, int n_in,
                              void* d_out, int out_size, void* d_ws, size_t ws_size,
                              hipStream_t stream)
{
    const float* Tt   = (const float*)d_in[0];
    const float* Bt   = (const float*)d_in[1];
    const float* Mt   = (const float*)d_in[2];
    const float* Wqkv = (const float*)d_in[3];
    const float* Wred = (const float*)d_in[4];
    const float* Wrec = (const float*)d_in[5];
    float* out = (float*)d_out;

    unsigned char* p = (unsigned char*)d_ws;
    u16* xT = (u16*)p;            p += (size_t)3 * Bn * HWn * Cn * 2;   // 25.2 MB
    u16* Mm = (u16*)p;            p += (size_t)Bn * 256 * 768 * 2;      // 1.57 MB
    unsigned char* zbase = p;
    u16* CWp = (u16*)p;           p += (size_t)3 * MP * Cn * 2;         // 983 KB
    float* pool_sum = (float*)p;  p += (size_t)27 * Bn * CPn * 4;
    u32*   pool_max = (u32*)p;    p += (size_t)27 * Bn * CPn * 4;
    float* coefA = (float*)p;     p += (size_t)3 * Bn * Cn * 4;
    float* coefK = (float*)p;     p += (size_t)3 * Bn * Cn * 4;
    const size_t zbytes = (size_t)(p - zbase);

    hipMemsetAsync(zbase, 0, zbytes, stream);

    compose_red      <<<dim3(4, 9, 3),    256, 0, stream>>>(Wqkv, Wred, CWp);
    convert_transpose<<<dim3(256, Bn, 3), 256, 0, stream>>>(Tt, Bt, Mt, xT);
    redpool_mfma     <<<dim3(320, 1, 3),  256, 0, stream>>>(xT, CWp, pool_sum, pool_max);
    attn_small       <<<9 * Bn,           256, 0, stream>>>(pool_sum, pool_max, Wrec, coefA, coefK);
    build_M          <<<dim3(768, Bn),    256, 0, stream>>>(Wqkv, coefA, coefK, Mm);
    final_mfma       <<<dim3(64, Bn),     256, 0, stream>>>(xT, Mm, out);
}